// Round 5
// baseline (49636.194 us; speedup 1.0000x reference)
//
#include <hip/hip_runtime.h>

#define HSZ 1024
#define TSTEPS 4096
#define NBLK 384
#define NTHR 256           // 4 waves/block x 384 blocks = 1536 waves, all resident
#define SLOTS 4
#define REP_DW 12288       // 3 arrays x 4 slots x 1024 tagged dwords
#define REP_BYTES 49152

typedef _Float16 half2v __attribute__((ext_vector_type(2)));
typedef unsigned long long ull;

#if __has_builtin(__builtin_amdgcn_fdot2)
#define FDOT2(a, b, c) __builtin_amdgcn_fdot2((a), (b), (c), false)
#else
__device__ __forceinline__ float FDOT2(half2v a, half2v b, float c) {
    return c + (float)a.x * (float)b.x + (float)a.y * (float)b.y;
}
#endif

__device__ __forceinline__ int f2i(float f) { int i; __builtin_memcpy(&i, &f, 4); return i; }
__device__ __forceinline__ float i2f(int i) { float f; __builtin_memcpy(&f, &i, 4); return f; }

template <int CTRL, int RM>
__device__ __forceinline__ float dpp_acc(float v) {
    int t = __builtin_amdgcn_update_dpp(0, f2i(v), CTRL, RM, 0xf, true);
    return v + i2f(t);
}
// Full 64-lane sum, valid on lanes 31 and 63 (units 0/1 of the wave in parallel).
__device__ __forceinline__ float red_unit(float v) {
    v = dpp_acc<0x111, 0xf>(v);  // row_shr:1
    v = dpp_acc<0x112, 0xf>(v);  // row_shr:2
    v = dpp_acc<0x114, 0xf>(v);  // row_shr:4
    v = dpp_acc<0x118, 0xf>(v);  // row_shr:8 -> lane15/31/47/63 row sums
    v = dpp_acc<0x142, 0xa>(v);  // lane31 += lane15 ; lane63 += lane47
    v += __shfl_xor(v, 32, 64);  // lanes 31,63 = full sum
    return v;
}
// Full 64-lane sum on lane 63 (head dot only).
__device__ __forceinline__ float wave_sum63(float v) {
    v = dpp_acc<0x111, 0xf>(v);
    v = dpp_acc<0x112, 0xf>(v);
    v = dpp_acc<0x114, 0xf>(v);
    v = dpp_acc<0x118, 0xf>(v);
    v = dpp_acc<0x142, 0xa>(v);
    v = dpp_acc<0x143, 0xc>(v);
    return v;
}

__device__ __forceinline__ float sigm(float x) { return 1.0f / (1.0f + __expf(-x)); }
__device__ __forceinline__ float tanh_fast(float x) {
    const float e = __expf(2.0f * x);
    return 1.0f - 2.0f / (e + 1.0f);
}

// ---- agent-coherent accesses (proven primitives) ----
__device__ __forceinline__ ull ld_coh64(const ull* p) {
    return __hip_atomic_load(p, __ATOMIC_RELAXED, __HIP_MEMORY_SCOPE_AGENT);
}
__device__ __forceinline__ void st_coh32(unsigned* p, unsigned v) {
    __hip_atomic_store(p, v, __ATOMIC_RELAXED, __HIP_MEMORY_SCOPE_AGENT);
}

__device__ __forceinline__ unsigned f16bits(float v) {
    _Float16 h = (_Float16)v;
    unsigned short b;
    __builtin_memcpy(&b, &h, 2);
    return (unsigned)b;
}

#define PINH(h) asm volatile("" : "+v"(h))

__device__ __forceinline__ half2v cvt2(float a, float b) {
    half2v r; r.x = (_Float16)a; r.y = (_Float16)b; return r;
}
__device__ __forceinline__ half2v bits_to_h2(unsigned v) {
    half2v h; __builtin_memcpy(&h, &v, 4); return h;
}
__device__ __forceinline__ unsigned pack_payload(ull q) {
#if __has_builtin(__builtin_amdgcn_perm)
    return __builtin_amdgcn_perm((unsigned)(q >> 32), (unsigned)q, 0x05040100u);
#else
    return ((unsigned)q & 0xFFFFu) | ((unsigned)(q >> 32) << 16);
#endif
}

// ---- polls: 8 qwords/lane cover one 1024-unit tagged array (no duplication:
// lane l holds h-elems {2l+128j, 2l+128j+1}). Weight fragments match. ----
struct Poll { ull q[8]; };

__device__ __forceinline__ Poll issueP(const ull* base, int lane) {
    Poll p;
#pragma unroll
    for (int j = 0; j < 8; ++j) p.q[j] = ld_coh64(base + lane + 64 * j);
    return p;
}

__device__ __forceinline__ bool chkE(const Poll& p, ull K) {
    ull bad = 0;
#pragma unroll
    for (int j = 0; j < 8; ++j) bad |= (p.q[j] ^ K);
    return __all((bad & 0xFFFF0000FFFF0000ull) == 0);
}

// Exact-tag critical poll, pipelined retry (one generation always in flight
// during the check of the previous one -> retry quantum ~L/2, not L+sleep).
__device__ __forceinline__ void completeP(Poll& p, const ull* base, unsigned e,
                                          int lane, half2v* hf) {
    const ull K = ((ull)e << 16) | ((ull)e << 48);
    if (!chkE(p, K)) {
        Poll p1 = issueP(base, lane);
        for (;;) {
            Poll p2 = issueP(base, lane);  // in flight while p1 is checked
            if (chkE(p1, K)) { p = p1; break; }
            p1 = p2;
        }
    }
#pragma unroll
    for (int j = 0; j < 8; ++j) hf[j] = bits_to_h2(pack_payload(p.q[j]));
}

// Back-pressure poll: all tags >= e (deep slack, first check normally passes).
__device__ __forceinline__ void completeBP(Poll& p, const ull* base, unsigned e,
                                           int lane) {
    for (;;) {
        unsigned mn = 0xFFFFu;
#pragma unroll
        for (int j = 0; j < 8; ++j) {
            unsigned t0 = (unsigned)((p.q[j] >> 16) & 0xFFFFu);
            unsigned t1 = (unsigned)(p.q[j] >> 48);
            mn = t0 < mn ? t0 : mn;
            mn = t1 < mn ? t1 : mn;
        }
        if (__all(mn >= e)) break;
        p = issueP(base, lane);
    }
}

__global__ void __launch_bounds__(NTHR, 2) lstm_persist(
    const float* __restrict__ x,
    const float* __restrict__ Wih0, const float* __restrict__ Whh0,
    const float* __restrict__ bih0, const float* __restrict__ bhh0,
    const float* __restrict__ Wih12, const float* __restrict__ Whh12,
    const float* __restrict__ bih12, const float* __restrict__ bhh12,
    const float* __restrict__ Wres, const float* __restrict__ bres,
    float* __restrict__ out, float* __restrict__ ws_f, int nrep)
{
    unsigned* wsd = (unsigned*)ws_f;
    const int lane = threadIdx.x & 63;
    const int gw = blockIdx.x * (NTHR / 64) + (threadIdx.x >> 6);
    const int layer = gw % 3;          // 512 waves per layer
    const int m = gw / 3;              // within-layer wave index, units 2m, 2m+1
    const int unit = 2 * m + (lane >> 5);

    // ---- init: all slots of all replicas = tag 0 / value 0 ----
    {
        const int gid = blockIdx.x * NTHR + threadIdx.x;
        if (gid < nrep * REP_DW) st_coh32(wsd + gid, 0u);
    }

    // ---- per-wave weights (f16, register-resident) and scalars ----
    // fragment j of row r = W[r][2*lane+128*j], W[r][2*lane+128*j+1]
    float bb[4];
    half2v wa[2][4][8], wb_[2][4][8];   // wa: first matrix, wb_: second (unused for L0)
    float wxa[4], wxb[4];

    if (layer == 0) {
        const float2* Wv = (const float2*)Whh0;
#pragma unroll
        for (int u = 0; u < 2; ++u)
#pragma unroll
            for (int q = 0; q < 4; ++q)
#pragma unroll
                for (int j = 0; j < 8; ++j) {
                    float2 t = Wv[(size_t)(q * HSZ + 2 * m + u) * 512 + lane + 64 * j];
                    wa[u][q][j] = cvt2(t.x, t.y);
                }
#pragma unroll
        for (int q = 0; q < 4; ++q) {
            const int r = q * HSZ + unit;
            wxa[q] = Wih0[2 * r];
            wxb[q] = Wih0[2 * r + 1];
            bb[q] = bih0[r] + bhh0[r];
        }
    } else {
        const size_t off = (layer == 2) ? (size_t)4 * HSZ * HSZ : 0;
        const float2* Wi = (const float2*)(Wih12 + off);
        const float2* Wh = (const float2*)(Whh12 + off);
#pragma unroll
        for (int u = 0; u < 2; ++u)
#pragma unroll
            for (int q = 0; q < 4; ++q)
#pragma unroll
                for (int j = 0; j < 8; ++j) {
                    const size_t r = (size_t)(q * HSZ + 2 * m + u) * 512 + lane + 64 * j;
                    float2 ti = Wi[r]; wa[u][q][j] = cvt2(ti.x, ti.y);
                    float2 th = Wh[r]; wb_[u][q][j] = cvt2(th.x, th.y);
                }
        const int boff = (layer == 2) ? 4 * HSZ : 0;
#pragma unroll
        for (int q = 0; q < 4; ++q)
            bb[q] = bih12[boff + q * HSZ + unit] + bhh12[boff + q * HSZ + unit];
    }
#pragma unroll
    for (int u = 0; u < 2; ++u)
#pragma unroll
        for (int q = 0; q < 4; ++q)
#pragma unroll
            for (int j = 0; j < 8; ++j) { PINH(wa[u][q][j]); PINH(wb_[u][q][j]); }

    const bool ishead = (layer == 2) && (m == 511);
    half2v wresh[8];
    float bres0 = 0.0f;
    if (layer == 2) {
        const float2* wr = (const float2*)Wres;
#pragma unroll
        for (int j = 0; j < 8; ++j) {
            float2 t = wr[lane + 64 * j];
            wresh[j] = cvt2(t.x, t.y);
        }
        bres0 = bres[0];
    }

    // Drain init stores before anyone can publish over them.
    asm volatile("s_waitcnt vmcnt(0)" ::: "memory");
    __syncthreads();

    // reader replica; writers fan out to all replicas
    const int rep_r = gw % nrep;
    const ull* R = (const ull*)(wsd + rep_r * REP_DW);
    const ull* A0r = R;                 // array0, qword base (slot stride 512)
    const ull* A1r = R + 2048;
    const ull* A2r = R + 4096;

    float c = 0.0f;   // cell state, lanes 31/63 only

    if (layer == 0) {
        Poll pr = issueP(A0r + 3 * 512, lane);   // h0(-1): slot3 tag0
        Poll pbp;
        for (int s = 0; s < TSTEPS; ++s) {
            const float x0 = x[2 * s], x1 = x[2 * s + 1];
            half2v haf[8];
            completeP(pr, A0r + ((s - 1) & 3) * 512, (unsigned)s, lane, haf);

            float a0[4] = {0, 0, 0, 0}, a1[4] = {0, 0, 0, 0};
#pragma unroll
            for (int j = 0; j < 8; ++j)
#pragma unroll
                for (int q = 0; q < 4; ++q) {
                    a0[q] = FDOT2(wa[0][q][j], haf[j], a0[q]);
                    a1[q] = FDOT2(wa[1][q][j], haf[j], a1[q]);
                }
#pragma unroll
            for (int q = 0; q < 4; ++q) { a0[q] = red_unit(a0[q]); a1[q] = red_unit(a1[q]); }

            if (s >= 4) completeBP(pbp, A1r + (s & 3) * 512, (unsigned)(s - 3), lane);

            if ((lane & 31) == 31) {
                const bool hi = lane >= 32;
                const float g0 = (hi ? a1[0] : a0[0]) + bb[0] + wxa[0] * x0 + wxb[0] * x1;
                const float g1 = (hi ? a1[1] : a0[1]) + bb[1] + wxa[1] * x0 + wxb[1] * x1;
                const float g2 = (hi ? a1[2] : a0[2]) + bb[2] + wxa[2] * x0 + wxb[2] * x1;
                const float g3 = (hi ? a1[3] : a0[3]) + bb[3] + wxa[3] * x0 + wxb[3] * x1;
                const float ig = sigm(g0), fg = sigm(g1);
                const float gg = tanh_fast(g2), og = sigm(g3);
                c = fg * c + ig * gg;
                const float h = og * tanh_fast(c);
                const unsigned wv = ((unsigned)(s + 1) << 16) | f16bits(h);
                for (int r = 0; r < nrep; ++r)
                    st_coh32(wsd + r * REP_DW + (s & 3) * 1024 + unit, wv);
            }
            pr = issueP(A0r + (s & 3) * 512, lane);
            if (s >= 3) pbp = issueP(A1r + ((s + 1) & 3) * 512, lane);
        }
    } else if (layer == 1) {
        Poll pr = issueP(A1r + 3 * 512, lane);   // h1(-1)
        Poll pi = issueP(A0r, lane);             // h0(0): slot0 tag1
        Poll pbp;
        for (int s = 0; s < TSTEPS; ++s) {
            half2v hbf[8], haf[8];
            completeP(pr, A1r + ((s - 1) & 3) * 512, (unsigned)s, lane, hbf);
            completeP(pi, A0r + (s & 3) * 512, (unsigned)(s + 1), lane, haf);

            float a0[4] = {0, 0, 0, 0}, a1[4] = {0, 0, 0, 0};
#pragma unroll
            for (int j = 0; j < 8; ++j)
#pragma unroll
                for (int q = 0; q < 4; ++q) {
                    a0[q] = FDOT2(wa[0][q][j], haf[j], a0[q]);
                    a0[q] = FDOT2(wb_[0][q][j], hbf[j], a0[q]);
                    a1[q] = FDOT2(wa[1][q][j], haf[j], a1[q]);
                    a1[q] = FDOT2(wb_[1][q][j], hbf[j], a1[q]);
                }
#pragma unroll
            for (int q = 0; q < 4; ++q) { a0[q] = red_unit(a0[q]); a1[q] = red_unit(a1[q]); }

            if (s >= 4) completeBP(pbp, A2r + (s & 3) * 512, (unsigned)(s - 3), lane);

            if ((lane & 31) == 31) {
                const bool hi = lane >= 32;
                const float ig = sigm((hi ? a1[0] : a0[0]) + bb[0]);
                const float fg = sigm((hi ? a1[1] : a0[1]) + bb[1]);
                const float gg = tanh_fast((hi ? a1[2] : a0[2]) + bb[2]);
                const float og = sigm((hi ? a1[3] : a0[3]) + bb[3]);
                c = fg * c + ig * gg;
                const float h = og * tanh_fast(c);
                const unsigned wv = ((unsigned)(s + 1) << 16) | f16bits(h);
                for (int r = 0; r < nrep; ++r)
                    st_coh32(wsd + r * REP_DW + 4096 + (s & 3) * 1024 + unit, wv);
            }
            pr = issueP(A1r + (s & 3) * 512, lane);
            pi = issueP(A0r + ((s + 1) & 3) * 512, lane);
            if (s >= 3) pbp = issueP(A2r + ((s + 1) & 3) * 512, lane);
        }
    } else {
        Poll pr = issueP(A2r + 3 * 512, lane);   // h2(-1)
        Poll pi = issueP(A1r, lane);             // h1(0)
        const int smax = ishead ? TSTEPS : (TSTEPS - 1);
        for (int s = 0; s <= smax; ++s) {
            half2v hcf[8];
            completeP(pr, A2r + ((s - 1) & 3) * 512, (unsigned)s, lane, hcf);

            if (s < TSTEPS) {
                half2v hbf[8];
                completeP(pi, A1r + (s & 3) * 512, (unsigned)(s + 1), lane, hbf);

                float a0[4] = {0, 0, 0, 0}, a1[4] = {0, 0, 0, 0};
#pragma unroll
                for (int j = 0; j < 8; ++j)
#pragma unroll
                    for (int q = 0; q < 4; ++q) {
                        a0[q] = FDOT2(wa[0][q][j], hbf[j], a0[q]);
                        a0[q] = FDOT2(wb_[0][q][j], hcf[j], a0[q]);
                        a1[q] = FDOT2(wa[1][q][j], hbf[j], a1[q]);
                        a1[q] = FDOT2(wb_[1][q][j], hcf[j], a1[q]);
                    }
#pragma unroll
                for (int q = 0; q < 4; ++q) { a0[q] = red_unit(a0[q]); a1[q] = red_unit(a1[q]); }

                if ((lane & 31) == 31) {
                    const bool hi = lane >= 32;
                    const float ig = sigm((hi ? a1[0] : a0[0]) + bb[0]);
                    const float fg = sigm((hi ? a1[1] : a0[1]) + bb[1]);
                    const float gg = tanh_fast((hi ? a1[2] : a0[2]) + bb[2]);
                    const float og = sigm((hi ? a1[3] : a0[3]) + bb[3]);
                    c = fg * c + ig * gg;
                    const float h = og * tanh_fast(c);
                    const unsigned wv = ((unsigned)(s + 1) << 16) | f16bits(h);
                    for (int r = 0; r < nrep; ++r)
                        st_coh32(wsd + r * REP_DW + 2 * 4096 + (s & 3) * 1024 + unit, wv);
                }
                pr = issueP(A2r + (s & 3) * 512, lane);
                pi = issueP(A1r + ((s + 1) & 3) * 512, lane);
            }

            // head: consume the recurrence snapshot h2(s-1) -> out[s-1]
            if (ishead && s >= 1) {
                float a = 0.0f;
#pragma unroll
                for (int j = 0; j < 8; ++j) a = FDOT2(wresh[j], hcf[j], a);
                a = wave_sum63(a);
                if (lane == 63) out[s - 1] = sigm(a + bres0);
            }
        }
    }
}

extern "C" void kernel_launch(void* const* d_in, const int* in_sizes, int n_in,
                              void* d_out, int out_size, void* d_ws, size_t ws_size,
                              hipStream_t stream) {
    const float* x     = (const float*)d_in[0];
    const float* Wih0  = (const float*)d_in[1];
    const float* Whh0  = (const float*)d_in[2];
    const float* bih0  = (const float*)d_in[3];
    const float* bhh0  = (const float*)d_in[4];
    const float* Wih12 = (const float*)d_in[5];
    const float* Whh12 = (const float*)d_in[6];
    const float* bih12 = (const float*)d_in[7];
    const float* bhh12 = (const float*)d_in[8];
    const float* Wres  = (const float*)d_in[9];
    const float* bres  = (const float*)d_in[10];
    float* out = (float*)d_out;
    float* ws  = (float*)d_ws;

    int nrep = (int)(ws_size / REP_BYTES);
    if (nrep > 8) nrep = 8;
    if (nrep < 1) nrep = 1;

    lstm_persist<<<dim3(NBLK), dim3(NTHR), 0, stream>>>(
        x, Wih0, Whh0, bih0, bhh0, Wih12, Whh12, bih12, bhh12,
        Wres, bres, out, ws, nrep);
}

// Round 6
// 28917.682 us; speedup vs baseline: 1.7165x; 1.7165x over previous
//
#include <hip/hip_runtime.h>

#define HSZ 1024
#define TSTEPS 4096
#define NBLK 256
#define NTHR 256           // 4 waves/block x 256 blocks = 1024 waves, 1/SIMD
#define REP_DW 12288       // 3 arrays x 4 slots x 1024 tagged dwords
#define REP_BYTES 49152

typedef _Float16 half2v __attribute__((ext_vector_type(2)));
typedef unsigned long long ull;

#if __has_builtin(__builtin_amdgcn_fdot2)
#define FDOT2(a, b, c) __builtin_amdgcn_fdot2((a), (b), (c), false)
#else
__device__ __forceinline__ float FDOT2(half2v a, half2v b, float c) {
    return c + (float)a.x * (float)b.x + (float)a.y * (float)b.y;
}
#endif

__device__ __forceinline__ int f2i(float f) { int i; __builtin_memcpy(&i, &f, 4); return i; }
__device__ __forceinline__ float i2f(int i) { float f; __builtin_memcpy(&f, &i, 4); return f; }

template <int CTRL, int RM>
__device__ __forceinline__ float dpp_acc(float v) {
    int t = __builtin_amdgcn_update_dpp(0, f2i(v), CTRL, RM, 0xf, true);
    return v + i2f(t);
}
// Full 64-lane sum valid on lanes 31 and 63 (the wave's two units in parallel).
__device__ __forceinline__ float red_unit(float v) {
    v = dpp_acc<0x111, 0xf>(v);  // row_shr:1
    v = dpp_acc<0x112, 0xf>(v);  // row_shr:2
    v = dpp_acc<0x114, 0xf>(v);  // row_shr:4
    v = dpp_acc<0x118, 0xf>(v);  // row_shr:8 -> lanes 15/31/47/63 hold row sums
    v = dpp_acc<0x142, 0xa>(v);  // lane31 += lane15 ; lane63 += lane47
    v += __shfl_xor(v, 32, 64);  // lanes 31,63 = full 64-lane sum
    return v;
}
// Full 64-lane sum on lane 63 (head dot only).
__device__ __forceinline__ float wave_sum63(float v) {
    v = dpp_acc<0x111, 0xf>(v);
    v = dpp_acc<0x112, 0xf>(v);
    v = dpp_acc<0x114, 0xf>(v);
    v = dpp_acc<0x118, 0xf>(v);
    v = dpp_acc<0x142, 0xa>(v);
    v = dpp_acc<0x143, 0xc>(v);
    return v;
}

__device__ __forceinline__ float sigm(float x) { return 1.0f / (1.0f + __expf(-x)); }
__device__ __forceinline__ float tanh_fast(float x) {
    const float e = __expf(2.0f * x);
    return 1.0f - 2.0f / (e + 1.0f);
}

// ---- agent-coherent accesses (proven primitives) ----
__device__ __forceinline__ ull ld_coh64(const ull* p) {
    return __hip_atomic_load(p, __ATOMIC_RELAXED, __HIP_MEMORY_SCOPE_AGENT);
}
__device__ __forceinline__ void st_coh32(unsigned* p, unsigned v) {
    __hip_atomic_store(p, v, __ATOMIC_RELAXED, __HIP_MEMORY_SCOPE_AGENT);
}

__device__ __forceinline__ unsigned f16bits(float v) {
    _Float16 h = (_Float16)v;
    unsigned short b;
    __builtin_memcpy(&b, &h, 2);
    return (unsigned)b;
}

#define PINH(h) asm volatile("" : "+v"(h))

__device__ __forceinline__ half2v cvt2(float a, float b) {
    half2v r; r.x = (_Float16)a; r.y = (_Float16)b; return r;
}
__device__ __forceinline__ half2v bits_to_h2(unsigned v) {
    half2v h; __builtin_memcpy(&h, &v, 4); return h;
}
__device__ __forceinline__ unsigned pack_payload(ull q) {
#if __has_builtin(__builtin_amdgcn_perm)
    return __builtin_amdgcn_perm((unsigned)(q >> 32), (unsigned)q, 0x05040100u);
#else
    return ((unsigned)q & 0xFFFFu) | ((unsigned)(q >> 32) << 16);
#endif
}

// ---- polls: 8 qwords/lane cover one 1024-unit tagged array.
// lane l fragment j = h elems {2l+128j, 2l+128j+1}; weight fragments match. ----
struct Poll { ull q[8]; };

__device__ __forceinline__ Poll issueP(const ull* base, int lane) {
    Poll p;
#pragma unroll
    for (int j = 0; j < 8; ++j) p.q[j] = ld_coh64(base + lane + 64 * j);
    return p;
}

__device__ __forceinline__ bool chkE(const Poll& p, ull K) {
    ull bad = 0;
#pragma unroll
    for (int j = 0; j < 8; ++j) bad |= (p.q[j] ^ K);
    return __all((bad & 0xFFFF0000FFFF0000ull) == 0);
}

// Exact-tag poll; sleep-backoff retry (bounded traffic, no hot loop).
__device__ __forceinline__ void completeP(Poll& p, const ull* base, unsigned e,
                                          int lane, half2v* hf) {
    const ull K = ((ull)e << 16) | ((ull)e << 48);
    if (!chkE(p, K)) {
        do {
            __builtin_amdgcn_s_sleep(1);
            p = issueP(base, lane);
        } while (!chkE(p, K));
    }
#pragma unroll
    for (int j = 0; j < 8; ++j) hf[j] = bits_to_h2(pack_payload(p.q[j]));
}

// Back-pressure poll: all tags >= e (deep slack; first check normally passes).
__device__ __forceinline__ void completeBP(Poll& p, const ull* base, unsigned e,
                                           int lane) {
    for (;;) {
        unsigned mn = 0xFFFFu;
#pragma unroll
        for (int j = 0; j < 8; ++j) {
            unsigned t0 = (unsigned)((p.q[j] >> 16) & 0xFFFFu);
            unsigned t1 = (unsigned)(p.q[j] >> 48);
            mn = t0 < mn ? t0 : mn;
            mn = t1 < mn ? t1 : mn;
        }
        if (__all(mn >= e)) break;
        __builtin_amdgcn_s_sleep(1);
        p = issueP(base, lane);
    }
}

__global__ void __launch_bounds__(NTHR, 1) lstm_persist(
    const float* __restrict__ x,
    const float* __restrict__ Wih0, const float* __restrict__ Whh0,
    const float* __restrict__ bih0, const float* __restrict__ bhh0,
    const float* __restrict__ Wih12, const float* __restrict__ Whh12,
    const float* __restrict__ bih12, const float* __restrict__ bhh12,
    const float* __restrict__ Wres, const float* __restrict__ bres,
    float* __restrict__ out, float* __restrict__ ws_f, int nrep)
{
    unsigned* wsd = (unsigned*)ws_f;
    const int lane = threadIdx.x & 63;
    const int wid = threadIdx.x >> 6;
    const bool is01 = (wid < 2);                 // waves 0,1: L0+L1 ; waves 2,3: L2
    const int m = blockIdx.x * 2 + (wid & 1);    // 0..511 within group
    const int unit = 2 * m + (lane >> 5);

    // ---- init: all slots/replicas = tag 0, value 0 ----
    {
        const int gid = blockIdx.x * NTHR + threadIdx.x;
        for (int d = gid; d < nrep * REP_DW; d += NBLK * NTHR) st_coh32(wsd + d, 0u);
    }

    // ---- weights (f16, register-resident) ----
    // L01: wA1=Wih1, wA2=Whh1 (phase_A=L1), wB=Whh0 (phase_B=L0)
    // L2 : wA1=Wih2, wA2=Whh2
    float bbA[4], bbB[4], wxa[4], wxb[4];
    half2v wA1[2][4][8], wA2[2][4][8], wB[2][4][8];

    if (is01) {
        const float2* Wb = (const float2*)Whh0;
        const float2* Wi = (const float2*)Wih12;
        const float2* Wh = (const float2*)Whh12;
#pragma unroll
        for (int u = 0; u < 2; ++u)
#pragma unroll
            for (int q = 0; q < 4; ++q)
#pragma unroll
                for (int j = 0; j < 8; ++j) {
                    const size_t idx = (size_t)(q * HSZ + 2 * m + u) * 512 + lane + 64 * j;
                    float2 tb = Wb[idx]; wB[u][q][j]  = cvt2(tb.x, tb.y);
                    float2 ti = Wi[idx]; wA1[u][q][j] = cvt2(ti.x, ti.y);
                    float2 th = Wh[idx]; wA2[u][q][j] = cvt2(th.x, th.y);
                }
#pragma unroll
        for (int q = 0; q < 4; ++q) {
            const int r = q * HSZ + unit;
            wxa[q] = Wih0[2 * r];
            wxb[q] = Wih0[2 * r + 1];
            bbB[q] = bih0[r] + bhh0[r];
            bbA[q] = bih12[r] + bhh12[r];
        }
    } else {
        const size_t off = (size_t)4 * HSZ * HSZ;
        const float2* Wi = (const float2*)(Wih12 + off);
        const float2* Wh = (const float2*)(Whh12 + off);
#pragma unroll
        for (int u = 0; u < 2; ++u)
#pragma unroll
            for (int q = 0; q < 4; ++q)
#pragma unroll
                for (int j = 0; j < 8; ++j) {
                    const size_t idx = (size_t)(q * HSZ + 2 * m + u) * 512 + lane + 64 * j;
                    float2 ti = Wi[idx]; wA1[u][q][j] = cvt2(ti.x, ti.y);
                    float2 th = Wh[idx]; wA2[u][q][j] = cvt2(th.x, th.y);
                }
#pragma unroll
        for (int q = 0; q < 4; ++q)
            bbA[q] = bih12[4 * HSZ + q * HSZ + unit] + bhh12[4 * HSZ + q * HSZ + unit];
    }
#pragma unroll
    for (int u = 0; u < 2; ++u)
#pragma unroll
        for (int q = 0; q < 4; ++q)
#pragma unroll
            for (int j = 0; j < 8; ++j) { PINH(wA1[u][q][j]); PINH(wA2[u][q][j]); PINH(wB[u][q][j]); }

    const bool ishead = (!is01) && (m == 0);
    half2v wresh[8];
    float bres0 = 0.0f;
    if (!is01) {
        const float2* wr = (const float2*)Wres;
#pragma unroll
        for (int j = 0; j < 8; ++j) {
            float2 t = wr[lane + 64 * j];
            wresh[j] = cvt2(t.x, t.y);
        }
        bres0 = bres[0];
    }

    // Drain init stores before anyone can publish over them.
    asm volatile("s_waitcnt vmcnt(0)" ::: "memory");
    __syncthreads();

    const int gw = blockIdx.x * 4 + wid;
    const int rep_r = gw % nrep;
    const ull* A0r = (const ull*)(wsd + rep_r * REP_DW);  // h0 (slot stride 512 qw)
    const ull* A1r = A0r + 2048;                           // h1
    const ull* A2r = A0r + 4096;                           // h2

    if (is01) {
        // ======== fused L0+L1 wave ========
        // iter n: phase_A computes L1 step n-2 (inputs: h0(n-2) reg-carried from
        // phase_B poll of iter n-1; h1(n-3) polled). phase_B computes L0 step n
        // (input h0(n-1) polled; also saved for next iter's phase_A).
        float cA = 0.0f, cB = 0.0f;   // c1, c0 on lanes 31/63
        half2v hsav[8];               // h0(n-2) for phase_A
        Poll pqh1 = issueP(A1r + 3 * 512, lane);  // first phase_A (n=2): h1(-1) slot3 tag0
        Poll pqh0 = issueP(A0r + 3 * 512, lane);  // first phase_B (n=0): h0(-1) slot3 tag0
        Poll pbp;

        for (int n = 0; n <= TSTEPS + 1; ++n) {
            // prefetch x early
            float x0 = 0.0f, x1 = 0.0f;
            if (n <= TSTEPS - 1) { x0 = x[2 * n]; x1 = x[2 * n + 1]; }

            // -------- phase_A: L1 step sA = n-2 --------
            if (n >= 2) {
                const int sA = n - 2;
                half2v hbf[8];
                completeP(pqh1, A1r + ((sA + 3) & 3) * 512, (unsigned)sA, lane, hbf);

                float a0[4] = {0, 0, 0, 0}, a1[4] = {0, 0, 0, 0};
#pragma unroll
                for (int j = 0; j < 8; ++j)
#pragma unroll
                    for (int q = 0; q < 4; ++q) {
                        a0[q] = FDOT2(wA1[0][q][j], hsav[j], a0[q]);
                        a0[q] = FDOT2(wA2[0][q][j], hbf[j], a0[q]);
                        a1[q] = FDOT2(wA1[1][q][j], hsav[j], a1[q]);
                        a1[q] = FDOT2(wA2[1][q][j], hbf[j], a1[q]);
                    }
#pragma unroll
                for (int q = 0; q < 4; ++q) { a0[q] = red_unit(a0[q]); a1[q] = red_unit(a1[q]); }

                // BP: before overwriting h1 ring slot sA&3, L2 must have consumed
                // h1(sA-4)  <=>  h2(sA-4) published (tag sA-3). ~3.5T slack.
                if (sA >= 4) completeBP(pbp, A2r + (sA & 3) * 512, (unsigned)(sA - 3), lane);

                if ((lane & 31) == 31) {
                    const bool hi = lane >= 32;
                    const float ig = sigm((hi ? a1[0] : a0[0]) + bbA[0]);
                    const float fg = sigm((hi ? a1[1] : a0[1]) + bbA[1]);
                    const float gg = tanh_fast((hi ? a1[2] : a0[2]) + bbA[2]);
                    const float og = sigm((hi ? a1[3] : a0[3]) + bbA[3]);
                    cA = fg * cA + ig * gg;
                    const float h = og * tanh_fast(cA);
                    const unsigned wv = ((unsigned)(sA + 1) << 16) | f16bits(h);
                    for (int r = 0; r < nrep; ++r)
                        st_coh32(wsd + r * REP_DW + 4096 + ((sA & 3) * 1024) + unit, wv);
                }
            }

            // -------- phase_B: L0 step n --------
            if (n <= TSTEPS) {
                half2v haf[8];
                completeP(pqh0, A0r + ((n + 3) & 3) * 512, (unsigned)n, lane, haf);
#pragma unroll
                for (int j = 0; j < 8; ++j) hsav[j] = haf[j];   // for next iter's phase_A

                if (n <= TSTEPS - 1) {
                    float a0[4] = {0, 0, 0, 0}, a1[4] = {0, 0, 0, 0};
#pragma unroll
                    for (int j = 0; j < 8; ++j)
#pragma unroll
                        for (int q = 0; q < 4; ++q) {
                            a0[q] = FDOT2(wB[0][q][j], haf[j], a0[q]);
                            a1[q] = FDOT2(wB[1][q][j], haf[j], a1[q]);
                        }
#pragma unroll
                    for (int q = 0; q < 4; ++q) { a0[q] = red_unit(a0[q]); a1[q] = red_unit(a1[q]); }

                    if ((lane & 31) == 31) {
                        const bool hi = lane >= 32;
                        const float g0 = (hi ? a1[0] : a0[0]) + bbB[0] + wxa[0] * x0 + wxb[0] * x1;
                        const float g1 = (hi ? a1[1] : a0[1]) + bbB[1] + wxa[1] * x0 + wxb[1] * x1;
                        const float g2 = (hi ? a1[2] : a0[2]) + bbB[2] + wxa[2] * x0 + wxb[2] * x1;
                        const float g3 = (hi ? a1[3] : a0[3]) + bbB[3] + wxa[3] * x0 + wxb[3] * x1;
                        const float ig = sigm(g0), fg = sigm(g1);
                        const float gg = tanh_fast(g2), og = sigm(g3);
                        cB = fg * cB + ig * gg;
                        const float h = og * tanh_fast(cB);
                        const unsigned wv = ((unsigned)(n + 1) << 16) | f16bits(h);
                        for (int r = 0; r < nrep; ++r)
                            st_coh32(wsd + r * REP_DW + ((n & 3) * 1024) + unit, wv);
                    }
                }
            }

            // -------- issue next-iter polls (end-of-iter slack) --------
            if (n >= 1 && n <= TSTEPS)
                pqh1 = issueP(A1r + ((n + 2) & 3) * 512, lane);   // h1(n-2), tag n-1
            if (n <= TSTEPS - 1)
                pqh0 = issueP(A0r + (n & 3) * 512, lane);         // h0(n), tag n+1
            if (n >= 5 && n <= TSTEPS)
                pbp = issueP(A2r + ((n + 3) & 3) * 512, lane);    // next BP slot
        }
    } else {
        // ======== L2 wave (+ head on m==0) ========
        float c = 0.0f;
        Poll pr = issueP(A2r + 3 * 512, lane);   // h2(-1): slot3 tag0
        Poll pi = issueP(A1r, lane);             // h1(0): slot0 tag1

        for (int i = 0; i <= TSTEPS; ++i) {
            half2v hcf[8];
            completeP(pr, A2r + ((i + 3) & 3) * 512, (unsigned)i, lane, hcf);

            if (i <= TSTEPS - 1) {
                half2v hbf[8];
                completeP(pi, A1r + (i & 3) * 512, (unsigned)(i + 1), lane, hbf);

                float a0[4] = {0, 0, 0, 0}, a1[4] = {0, 0, 0, 0};
#pragma unroll
                for (int j = 0; j < 8; ++j)
#pragma unroll
                    for (int q = 0; q < 4; ++q) {
                        a0[q] = FDOT2(wA1[0][q][j], hbf[j], a0[q]);
                        a0[q] = FDOT2(wA2[0][q][j], hcf[j], a0[q]);
                        a1[q] = FDOT2(wA1[1][q][j], hbf[j], a1[q]);
                        a1[q] = FDOT2(wA2[1][q][j], hcf[j], a1[q]);
                    }
#pragma unroll
                for (int q = 0; q < 4; ++q) { a0[q] = red_unit(a0[q]); a1[q] = red_unit(a1[q]); }

                if ((lane & 31) == 31) {
                    const bool hi = lane >= 32;
                    const float ig = sigm((hi ? a1[0] : a0[0]) + bbA[0]);
                    const float fg = sigm((hi ? a1[1] : a0[1]) + bbA[1]);
                    const float gg = tanh_fast((hi ? a1[2] : a0[2]) + bbA[2]);
                    const float og = sigm((hi ? a1[3] : a0[3]) + bbA[3]);
                    c = fg * c + ig * gg;
                    const float h = og * tanh_fast(c);
                    const unsigned wv = ((unsigned)(i + 1) << 16) | f16bits(h);
                    for (int r = 0; r < nrep; ++r)
                        st_coh32(wsd + r * REP_DW + 8192 + ((i & 3) * 1024) + unit, wv);
                }
                pr = issueP(A2r + (i & 3) * 512, lane);
                pi = issueP(A1r + ((i + 1) & 3) * 512, lane);
            }

            // head: hcf = h2(i-1) -> out[i-1] (off the publish critical path)
            if (ishead && i >= 1) {
                float a = 0.0f;
#pragma unroll
                for (int j = 0; j < 8; ++j) a = FDOT2(wresh[j], hcf[j], a);
                a = wave_sum63(a);
                if (lane == 63) out[i - 1] = sigm(a + bres0);
            }
        }
    }
}

extern "C" void kernel_launch(void* const* d_in, const int* in_sizes, int n_in,
                              void* d_out, int out_size, void* d_ws, size_t ws_size,
                              hipStream_t stream) {
    const float* x     = (const float*)d_in[0];
    const float* Wih0  = (const float*)d_in[1];
    const float* Whh0  = (const float*)d_in[2];
    const float* bih0  = (const float*)d_in[3];
    const float* bhh0  = (const float*)d_in[4];
    const float* Wih12 = (const float*)d_in[5];
    const float* Whh12 = (const float*)d_in[6];
    const float* bih12 = (const float*)d_in[7];
    const float* bhh12 = (const float*)d_in[8];
    const float* Wres  = (const float*)d_in[9];
    const float* bres  = (const float*)d_in[10];
    float* out = (float*)d_out;
    float* ws  = (float*)d_ws;

    int nrep = (int)(ws_size / REP_BYTES);
    if (nrep > 8) nrep = 8;
    if (nrep < 1) nrep = 1;

    lstm_persist<<<dim3(NBLK), dim3(NTHR), 0, stream>>>(
        x, Wih0, Whh0, bih0, bhh0, Wih12, Whh12, bih12, bhh12,
        Wres, bres, out, ws, nrep);
}

// Round 7
// 12890.956 us; speedup vs baseline: 3.8505x; 2.2433x over previous
//
#include <hip/hip_runtime.h>

#define HSZ 1024
#define TSTEPS 4096
#define NBLK 256
#define NTHR 256   // 4 waves/block x 256 blocks = 1024 waves == HSZ units
#define HV (HSZ / 4)
#define REP_BYTES 24576  // one replica: [2 parity][3 array][1024 tagged dwords]

typedef _Float16 half2v __attribute__((ext_vector_type(2)));
typedef unsigned long long ull;

#if __has_builtin(__builtin_amdgcn_fdot2)
#define FDOT2(a, b, c) __builtin_amdgcn_fdot2((a), (b), (c), false)
#else
__device__ __forceinline__ float FDOT2(half2v a, half2v b, float c) {
    return c + (float)a.x * (float)b.x + (float)a.y * (float)b.y;
}
#endif

__device__ __forceinline__ int f2i(float f) { int i; __builtin_memcpy(&i, &f, 4); return i; }
__device__ __forceinline__ float i2f(int i) { float f; __builtin_memcpy(&f, &i, 4); return f; }

// ---- DPP wave reduction: full 64-lane sum lands on lane 63 (VALU-rate) ----
template <int CTRL, int RM>
__device__ __forceinline__ float dpp_acc(float v) {
    int t = __builtin_amdgcn_update_dpp(0, f2i(v), CTRL, RM, 0xf, true);
    return v + i2f(t);
}
__device__ __forceinline__ float wave_sum63(float v) {
    v = dpp_acc<0x111, 0xf>(v);  // row_shr:1
    v = dpp_acc<0x112, 0xf>(v);  // row_shr:2
    v = dpp_acc<0x114, 0xf>(v);  // row_shr:4
    v = dpp_acc<0x118, 0xf>(v);  // row_shr:8  -> lane15/31/47/63 hold row sums
    v = dpp_acc<0x142, 0xa>(v);  // row_bcast:15 (rows 1,3 only)
    v = dpp_acc<0x143, 0xc>(v);  // row_bcast:31 (rows 2,3 only) -> lane63 = total
    return v;
}

__device__ __forceinline__ float sigm(float x) { return 1.0f / (1.0f + __expf(-x)); }
__device__ __forceinline__ float tanh_fast(float x) {
    const float e = __expf(2.0f * x);
    return 1.0f - 2.0f / (e + 1.0f);
}

// ---- agent-coherent (L3-level) accesses, no cache fences ----
__device__ __forceinline__ ull ld_coh64(const ull* p) {
    return __hip_atomic_load(p, __ATOMIC_RELAXED, __HIP_MEMORY_SCOPE_AGENT);
}
__device__ __forceinline__ void st_coh32(unsigned* p, unsigned v) {
    __hip_atomic_store(p, v, __ATOMIC_RELAXED, __HIP_MEMORY_SCOPE_AGENT);
}

__device__ __forceinline__ unsigned f16bits(float v) {
    _Float16 h = (_Float16)v;
    unsigned short b;
    __builtin_memcpy(&b, &h, 2);
    return (unsigned)b;
}

// Pin packed-f16 weight into a VGPR (prevents load re-sinking).
#define PINH(h) asm volatile("" : "+v"(h))

// f32->half2 (init path, RNE per element)
__device__ __forceinline__ half2v cvt2(float a, float b) {
    half2v r; r.x = (_Float16)a; r.y = (_Float16)b; return r;
}

__device__ __forceinline__ half2v bits_to_h2(unsigned v) {
    half2v h; __builtin_memcpy(&h, &v, 4); return h;
}

// strip two 16-bit tags from a tagged-dword pair -> packed f16 pair (1 v_perm)
__device__ __forceinline__ unsigned pack_payload(ull q) {
#if __has_builtin(__builtin_amdgcn_perm)
    return __builtin_amdgcn_perm((unsigned)(q >> 32), (unsigned)q, 0x05040100u);
#else
    return ((unsigned)q & 0xFFFFu) | ((unsigned)(q >> 32) << 16);
#endif
}

// ---- per-WAVE register-direct poll (champion R4 geometry): 8 coalesced b64
// loads/lane cover one 1024-unit tagged array. Split-phase: issued one phase
// ahead (2T/3 slack after publish), checked one phase later (T/3 flight). ----
struct PollA { ull q[8]; };

__device__ __forceinline__ PollA poll_issueA(const ull* A, int lane) {
    PollA p;
#pragma unroll
    for (int i = 0; i < 4; ++i) {
        p.q[2 * i]     = ld_coh64(A + 2 * lane + 128 * i);
        p.q[2 * i + 1] = ld_coh64(A + 2 * lane + 128 * i + 1);
    }
    return p;
}

// Selective-lane retry; FIRST retry immediate (no sleep) to catch marginal
// misses at the V-equilibrium cheaply, sleep-backoff from the 2nd retry on.
__device__ __forceinline__ void poll_completeA(PollA& p, const ull* A,
                                               unsigned e, int lane, half2v* hf) {
    const ull K = ((ull)e << 16) | ((ull)e << 48);
    ull bad = 0;
#pragma unroll
    for (int j = 0; j < 8; ++j) bad |= (p.q[j] ^ K);
    bad &= 0xFFFF0000FFFF0000ull;
    bool first = true;
    while (!__all(bad == 0)) {
        if (!first) __builtin_amdgcn_s_sleep(1);
        first = false;
        if (bad) {  // divergent: only stale lanes reload
#pragma unroll
            for (int i = 0; i < 4; ++i) {
                p.q[2 * i]     = ld_coh64(A + 2 * lane + 128 * i);
                p.q[2 * i + 1] = ld_coh64(A + 2 * lane + 128 * i + 1);
            }
            bad = 0;
#pragma unroll
            for (int j = 0; j < 8; ++j) bad |= (p.q[j] ^ K);
            bad &= 0xFFFF0000FFFF0000ull;
        }
    }
#pragma unroll
    for (int j = 0; j < 8; ++j) hf[j] = bits_to_h2(pack_payload(p.q[j]));
}

__global__ void __launch_bounds__(NTHR, 1) lstm_persist(
    const float* __restrict__ x,
    const float* __restrict__ Wih0, const float* __restrict__ Whh0,
    const float* __restrict__ bih0, const float* __restrict__ bhh0,
    const float* __restrict__ Wih12, const float* __restrict__ Whh12,
    const float* __restrict__ bih12, const float* __restrict__ bhh12,
    const float* __restrict__ Wres, const float* __restrict__ bres,
    float* __restrict__ out, float* __restrict__ ws_f, int nrep)
{
    char* wsb = (char*)ws_f;
    const int lane = threadIdx.x & 63;
    const int u = blockIdx.x * (NTHR / 64) + (threadIdx.x >> 6);  // hidden unit
    const int tid = threadIdx.x;

    // ---- init: parity 1 of every replica = tag 0, value 0 ----
    {
        const int gid = blockIdx.x * NTHR + tid;
        if (gid < nrep * 3072) {
            const int rep = gid / 3072, d = gid % 3072;
            st_coh32((unsigned*)(wsb + rep * REP_BYTES) + 3072 + d, 0u);
        }
    }

    // ---- per-wave scalar constants ----
    float b0[4], b1[4], b2[4], wx0a[4], wx0b[4];
#pragma unroll
    for (int g = 0; g < 4; ++g) {
        const int r = g * HSZ + u;
        b0[g] = bih0[r] + bhh0[r];
        b1[g] = bih12[r] + bhh12[r];
        b2[g] = bih12[4 * HSZ + r] + bhh12[4 * HSZ + r];
        wx0a[g] = Wih0[2 * r];
        wx0b[g] = Wih0[2 * r + 1];
    }

    // ---- register-resident f16 weights: 20 rows x 1024 -> 160 half2/lane ----
    const float4* Whh0v = (const float4*)Whh0;
    const float4* Wih1v = (const float4*)Wih12;
    const float4* Whh1v = (const float4*)Whh12;
    const float4* Wih2v = (const float4*)(Wih12 + 4 * HSZ * HSZ);
    const float4* Whh2v = (const float4*)(Whh12 + 4 * HSZ * HSZ);

    half2v w0h[4][8], wi1h[4][8], wh1h[4][8], wi2h[4][8], wh2h[4][8];
#pragma unroll
    for (int g = 0; g < 4; ++g) {
        const size_t r = (size_t)(g * HSZ + u) * HV + lane;
#pragma unroll
        for (int i = 0; i < 4; ++i) {
            float4 t;
            t = Whh0v[r + 64 * i];  w0h[g][2*i] = cvt2(t.x,t.y);  w0h[g][2*i+1] = cvt2(t.z,t.w);
            t = Wih1v[r + 64 * i];  wi1h[g][2*i] = cvt2(t.x,t.y); wi1h[g][2*i+1] = cvt2(t.z,t.w);
            t = Whh1v[r + 64 * i];  wh1h[g][2*i] = cvt2(t.x,t.y); wh1h[g][2*i+1] = cvt2(t.z,t.w);
            t = Wih2v[r + 64 * i];  wi2h[g][2*i] = cvt2(t.x,t.y); wi2h[g][2*i+1] = cvt2(t.z,t.w);
            t = Whh2v[r + 64 * i];  wh2h[g][2*i] = cvt2(t.x,t.y); wh2h[g][2*i+1] = cvt2(t.z,t.w);
        }
    }
#pragma unroll
    for (int g = 0; g < 4; ++g)
#pragma unroll
        for (int j = 0; j < 8; ++j) {
            PINH(w0h[g][j]); PINH(wi1h[g][j]); PINH(wh1h[g][j]);
            PINH(wi2h[g][j]); PINH(wh2h[g][j]);
        }

    // head weights as f16 (distributed head: every wave serves 4 of 4096 steps)
    half2v wresh[8];
    {
        const float4* wr = (const float4*)Wres;
#pragma unroll
        for (int i = 0; i < 4; ++i) {
            float4 t = wr[lane + 64 * i];
            wresh[2*i] = cvt2(t.x, t.y); wresh[2*i+1] = cvt2(t.z, t.w);
        }
    }
    const float bres0 = bres[0];

    // Drain init stores so no late init write can clobber a live tagged word.
    asm volatile("s_waitcnt vmcnt(0)" ::: "memory");
    __syncthreads();

    const ull* Tmyq = (const ull*)(wsb + (blockIdx.x % nrep) * REP_BYTES);

    float c0 = 0.0f, c1 = 0.0f, c2 = 0.0f;  // live on lane 63 only

    // R4 wavefront pipeline, split-phase polls (uniform slack geometry):
    //   iter k: check pq0 -> issue pq1 -> L0 -> pub h0
    //           -> check pq1 -> issue pq2 -> L1 -> pub h1
    //           -> check pq2 -> issue pq0(next parity) -> L2 -> pub h2 -> head?
    PollA pq0 = poll_issueA(Tmyq + 1536, lane);  // k=0 reads parity 1, array 0

    for (int k = 0; k <= TSTEPS + 2; ++k) {
        const int wp = k & 1, rp = wp ^ 1;
        const unsigned e = (unsigned)k;
        const ull* Trp = Tmyq + rp * 1536;
        const ull* Tnx = Tmyq + wp * 1536;  // next iter's read parity
        const bool pub = (k <= TSTEPS + 1);
        const unsigned tg = (unsigned)(k + 1) << 16;

        // prefetch x before the poll-wait (hides the load latency)
        float x0 = 0.0f, x1 = 0.0f;
        if (k < TSTEPS) { x0 = x[2 * k]; x1 = x[2 * k + 1]; }

        // ================= layer 0 =================
        half2v haf[8];
        poll_completeA(pq0, Trp, e, lane, haf);
        PollA pq1 = poll_issueA(Trp + 512, lane);  // in flight during L0

        float h0v = 0.0f;
        if (k < TSTEPS) {
            float acc[4];
#pragma unroll
            for (int g = 0; g < 4; ++g) {
                float a = 0.0f;
#pragma unroll
                for (int j = 0; j < 8; ++j) a = FDOT2(w0h[g][j], haf[j], a);
                acc[g] = a;
            }
#pragma unroll
            for (int g = 0; g < 4; ++g) acc[g] = wave_sum63(acc[g]);
            if (lane == 63) {
                const float ig = sigm(acc[0] + b0[0] + wx0a[0] * x0 + wx0b[0] * x1);
                const float fg = sigm(acc[1] + b0[1] + wx0a[1] * x0 + wx0b[1] * x1);
                const float gg = tanh_fast(acc[2] + b0[2] + wx0a[2] * x0 + wx0b[2] * x1);
                const float og = sigm(acc[3] + b0[3] + wx0a[3] * x0 + wx0b[3] * x1);
                c0 = fg * c0 + ig * gg;
                h0v = og * tanh_fast(c0);
            }
        }
        if (lane == 63 && pub) {
            const unsigned wb = tg | f16bits(h0v);
            for (int rep = 0; rep < nrep; ++rep)
                st_coh32((unsigned*)(wsb + rep * REP_BYTES) + wp * 3072 + u, wb);
        }

        // ================= layer 1 =================
        half2v hbf[8];
        poll_completeA(pq1, Trp + 512, e, lane, hbf);
        PollA pq2 = poll_issueA(Trp + 1024, lane);  // in flight during L1

        float h1v = 0.0f;
        if (k >= 1 && k <= TSTEPS) {
            float acc[4];
#pragma unroll
            for (int g = 0; g < 4; ++g) {
                float a = 0.0f;
#pragma unroll
                for (int j = 0; j < 8; ++j) {
                    a = FDOT2(wi1h[g][j], haf[j], a);
                    a = FDOT2(wh1h[g][j], hbf[j], a);
                }
                acc[g] = a;
            }
#pragma unroll
            for (int g = 0; g < 4; ++g) acc[g] = wave_sum63(acc[g]);
            if (lane == 63) {
                const float ig = sigm(acc[0] + b1[0]);
                const float fg = sigm(acc[1] + b1[1]);
                const float gg = tanh_fast(acc[2] + b1[2]);
                const float og = sigm(acc[3] + b1[3]);
                c1 = fg * c1 + ig * gg;
                h1v = og * tanh_fast(c1);
            }
        }
        if (lane == 63 && pub) {
            const unsigned wb = tg | f16bits(h1v);
            for (int rep = 0; rep < nrep; ++rep)
                st_coh32((unsigned*)(wsb + rep * REP_BYTES) + wp * 3072 + 1024 + u, wb);
        }

        // ================= layer 2 =================
        half2v hcf[8];
        poll_completeA(pq2, Trp + 1024, e, lane, hcf);
        pq0 = poll_issueA(Tnx, lane);  // next iter's array 0, in flight during L2

        float h2v = 0.0f;
        if (k >= 2 && k <= TSTEPS + 1) {
            float acc[4];
#pragma unroll
            for (int g = 0; g < 4; ++g) {
                float a = 0.0f;
#pragma unroll
                for (int j = 0; j < 8; ++j) {
                    a = FDOT2(wi2h[g][j], hbf[j], a);
                    a = FDOT2(wh2h[g][j], hcf[j], a);
                }
                acc[g] = a;
            }
#pragma unroll
            for (int g = 0; g < 4; ++g) acc[g] = wave_sum63(acc[g]);
            if (lane == 63) {
                const float ig = sigm(acc[0] + b2[0]);
                const float fg = sigm(acc[1] + b2[1]);
                const float gg = tanh_fast(acc[2] + b2[2]);
                const float og = sigm(acc[3] + b2[3]);
                c2 = fg * c2 + ig * gg;
                h2v = og * tanh_fast(c2);
            }
        }
        if (lane == 63 && pub) {
            const unsigned wb = tg | f16bits(h2v);
            for (int rep = 0; rep < nrep; ++rep)
                st_coh32((unsigned*)(wsb + rep * REP_BYTES) + wp * 3072 + 2048 + u, wb);
        }

        // ===== distributed head: out[t] served by wave t&1023 (4 per wave
        // total; wave-uniform branch, no permanent straggler) =====
        if (k >= 3 && ((k - 3) & (HSZ - 1)) == u) {
            float a = 0.0f;
#pragma unroll
            for (int j = 0; j < 8; ++j) a = FDOT2(wresh[j], hcf[j], a);
            a = wave_sum63(a);
            if (lane == 63) out[k - 3] = sigm(a + bres0);
        }
    }
}

extern "C" void kernel_launch(void* const* d_in, const int* in_sizes, int n_in,
                              void* d_out, int out_size, void* d_ws, size_t ws_size,
                              hipStream_t stream) {
    const float* x     = (const float*)d_in[0];
    const float* Wih0  = (const float*)d_in[1];
    const float* Whh0  = (const float*)d_in[2];
    const float* bih0  = (const float*)d_in[3];
    const float* bhh0  = (const float*)d_in[4];
    const float* Wih12 = (const float*)d_in[5];
    const float* Whh12 = (const float*)d_in[6];
    const float* bih12 = (const float*)d_in[7];
    const float* bhh12 = (const float*)d_in[8];
    const float* Wres  = (const float*)d_in[9];
    const float* bres  = (const float*)d_in[10];
    float* out = (float*)d_out;
    float* ws  = (float*)d_ws;

    int nrep = (int)(ws_size / REP_BYTES);
    if (nrep > 8) nrep = 8;
    if (nrep < 1) nrep = 1;

    lstm_persist<<<dim3(NBLK), dim3(NTHR), 0, stream>>>(
        x, Wih0, Whh0, bih0, bhh0, Wih12, Whh12, bih12, bhh12,
        Wres, bres, out, ws, nrep);
}